// Round 1
// baseline (111.224 us; speedup 1.0000x reference)
//
#include <hip/hip_runtime.h>
#include <hip/hip_bf16.h>

// DistanceProbe: out[b,i,j] = || (batch@proj)[b,i,:] - (batch@proj)[b,j,:] ||^2
// batch: [8,512,1024] fp32, proj: [1024,128] fp32, out: [8,512,512] fp32.
//
// Phase 1: T = batch@proj (M=4096,K=1024,N=128) + fused row norms.
// Phase 2: D = n_i + n_j - 2 * T T^T per batch (Gram trick).

#define B_DIM 8
#define S_DIM 512
#define M_DIM 1024
#define R_DIM 128
#define M_ROWS (B_DIM * S_DIM)  // 4096

// Device-global scratch (avoids ws_size assumptions). Fully rewritten every call.
__device__ float g_T[M_ROWS * R_DIM];   // 2 MB
__device__ float g_norms[M_ROWS];       // 16 KB

// ---------------- Phase 1: GEMM + norms ----------------
// BM=16, BN=128 (all), BK=32. 256 threads; thread = (tx 0..31: 4 cols, ty 0..7: 2 rows).
// grid 256 blocks -> 1 block/CU.
__global__ __launch_bounds__(256) void transform_kernel(
    const float* __restrict__ batch, const float* __restrict__ proj) {
  __shared__ float As[32][18];    // [k][m] transposed, pad 16->18 (b64 reads stay aligned, 2-way max)
  __shared__ float Bs[32][128];   // [k][n]
  const int tid = threadIdx.x;
  const int m0 = blockIdx.x * 16;
  const int tx = tid & 31;   // col group: cols 4tx..4tx+3
  const int ty = tid >> 5;   // row group: rows 2ty, 2ty+1

  // global-load assignments
  const int lam = tid >> 4;          // A row 0..15
  const int lak = (tid & 15) << 1;   // A k 0..30 (float2)
  const int lbr = tid >> 5;          // B row 0..7 (+8*i)
  const int lbc = (tid & 31) << 2;   // B col (float4)

  float acc[2][4] = {};

  for (int k0 = 0; k0 < M_DIM; k0 += 32) {
    // global loads first (no LDS dependence), then barrier, then LDS store
    const float2 av = *(const float2*)(batch + (size_t)(m0 + lam) * M_DIM + k0 + lak);
    const float4 bv0 = *(const float4*)(proj + (size_t)(k0 + lbr) * R_DIM + lbc);
    const float4 bv1 = *(const float4*)(proj + (size_t)(k0 + lbr + 8) * R_DIM + lbc);
    const float4 bv2 = *(const float4*)(proj + (size_t)(k0 + lbr + 16) * R_DIM + lbc);
    const float4 bv3 = *(const float4*)(proj + (size_t)(k0 + lbr + 24) * R_DIM + lbc);
    __syncthreads();  // protect previous iteration's LDS reads
    As[lak][lam] = av.x;
    As[lak + 1][lam] = av.y;
    *(float4*)(&Bs[lbr][lbc]) = bv0;
    *(float4*)(&Bs[lbr + 8][lbc]) = bv1;
    *(float4*)(&Bs[lbr + 16][lbc]) = bv2;
    *(float4*)(&Bs[lbr + 24][lbc]) = bv3;
    __syncthreads();

#pragma unroll
    for (int k = 0; k < 32; k++) {
      const float2 a = *(const float2*)(&As[k][ty << 1]);   // 2 addrs/wave: broadcast
      const float4 b = *(const float4*)(&Bs[k][tx << 2]);   // contiguous chunks: conflict-free
      acc[0][0] = fmaf(a.x, b.x, acc[0][0]);
      acc[0][1] = fmaf(a.x, b.y, acc[0][1]);
      acc[0][2] = fmaf(a.x, b.z, acc[0][2]);
      acc[0][3] = fmaf(a.x, b.w, acc[0][3]);
      acc[1][0] = fmaf(a.y, b.x, acc[1][0]);
      acc[1][1] = fmaf(a.y, b.y, acc[1][1]);
      acc[1][2] = fmaf(a.y, b.z, acc[1][2]);
      acc[1][3] = fmaf(a.y, b.w, acc[1][3]);
    }
  }

  // store T + fused norms (reduce squared sums over the 32 tx lanes)
#pragma unroll
  for (int r = 0; r < 2; r++) {
    const int row = m0 + (ty << 1) + r;
    *(float4*)(&g_T[(size_t)row * R_DIM + (tx << 2)]) =
        make_float4(acc[r][0], acc[r][1], acc[r][2], acc[r][3]);
    float p = acc[r][0] * acc[r][0] + acc[r][1] * acc[r][1] +
              acc[r][2] * acc[r][2] + acc[r][3] * acc[r][3];
#pragma unroll
    for (int off = 16; off >= 1; off >>= 1) p += __shfl_xor(p, off, 64);
    if (tx == 0) g_norms[row] = p;
  }
}

// ---------------- Phase 2: pairwise distances ----------------
// Per batch, 64x64 output tile per block. 256 threads = (tx 0..15, ty 0..15).
// Thread owns rows i = ty+16q and cols j = tx+16q (scattered: keeps b128 LDS reads 2-way max).
__global__ __launch_bounds__(256) void dist_kernel(float* __restrict__ out) {
  __shared__ float Ti[64][132];  // pad 128->132 (keeps float4 alignment, spreads banks)
  __shared__ float Tj[64][132];
  const int tid = threadIdx.x;
  const int b = blockIdx.z;
  const int i0 = blockIdx.y * 64;
  const int j0 = blockIdx.x * 64;
  const int tx = tid & 15;
  const int ty = tid >> 4;

  const float* Tb = g_T + (size_t)b * S_DIM * R_DIM;
  const int lr = tid >> 5;          // 0..7
  const int lc = (tid & 31) << 2;   // 0..124
#pragma unroll
  for (int p = 0; p < 8; p++) {
    const int row = (p << 3) + lr;
    const float4 vi = *(const float4*)(Tb + (size_t)(i0 + row) * R_DIM + lc);
    const float4 vj = *(const float4*)(Tb + (size_t)(j0 + row) * R_DIM + lc);
    *(float4*)(&Ti[row][lc]) = vi;
    *(float4*)(&Tj[row][lc]) = vj;
  }
  __syncthreads();

  float acc[4][4] = {};
  for (int r = 0; r < R_DIM; r += 4) {
    float4 a[4], bj[4];
#pragma unroll
    for (int q = 0; q < 4; q++) a[q] = *(const float4*)(&Ti[ty + (q << 4)][r]);
#pragma unroll
    for (int q = 0; q < 4; q++) bj[q] = *(const float4*)(&Tj[tx + (q << 4)][r]);
#pragma unroll
    for (int ri = 0; ri < 4; ri++) {
#pragma unroll
      for (int rj = 0; rj < 4; rj++) {
        acc[ri][rj] = fmaf(a[ri].x, bj[rj].x, acc[ri][rj]);
        acc[ri][rj] = fmaf(a[ri].y, bj[rj].y, acc[ri][rj]);
        acc[ri][rj] = fmaf(a[ri].z, bj[rj].z, acc[ri][rj]);
        acc[ri][rj] = fmaf(a[ri].w, bj[rj].w, acc[ri][rj]);
      }
    }
  }

  const float* nb = g_norms + b * S_DIM;
  float ni[4], nj[4];
#pragma unroll
  for (int q = 0; q < 4; q++) {
    ni[q] = nb[i0 + ty + (q << 4)];
    nj[q] = nb[j0 + tx + (q << 4)];
  }
  float* ob = out + (size_t)b * S_DIM * S_DIM;
#pragma unroll
  for (int ri = 0; ri < 4; ri++) {
    const int i = i0 + ty + (ri << 4);
#pragma unroll
    for (int rj = 0; rj < 4; rj++) {
      const int j = j0 + tx + (rj << 4);
      ob[(size_t)i * S_DIM + j] = ni[ri] + nj[rj] - 2.0f * acc[ri][rj];
    }
  }
}

extern "C" void kernel_launch(void* const* d_in, const int* in_sizes, int n_in,
                              void* d_out, int out_size, void* d_ws, size_t ws_size,
                              hipStream_t stream) {
  const float* batch = (const float*)d_in[0];
  const float* proj = (const float*)d_in[1];
  float* out = (float*)d_out;
  hipLaunchKernelGGL(transform_kernel, dim3(M_ROWS / 16), dim3(256), 0, stream,
                     batch, proj);
  hipLaunchKernelGGL(dist_kernel, dim3(8, 8, 8), dim3(256), 0, stream, out);
}

// Round 3
// 81.147 us; speedup vs baseline: 1.3706x; 1.3706x over previous
//
#include <hip/hip_runtime.h>
#include <hip/hip_bf16.h>

// DistanceProbe via bf16 MFMA:
//   T = batch@proj  (M=4096, K=1024, N=128), stored bf16 fragment-major
//   D[b,i,j] = n_i + n_j - 2*(T T^T)[b,i,j], norms from bf16-rounded T
//
// Kernel 0: proj fp32 [1024][128] -> g_projB bf16 frag-major [k/8][n][k&7]
// Kernel 1: GEMM (MFMA 16x16x32 bf16), BM=16, BK=64, dbuf reg-prefetch,
//           fused norms + bf16 T store (frag-major per batch)
// Kernel 2: Gram + distance epilogue, fragments loaded straight from L2.

#define S_DIM 512
#define K_DIM 1024
#define R_DIM 128
#define M_ROWS 4096  // 8*512

typedef __attribute__((ext_vector_type(8))) short short8;
typedef __attribute__((ext_vector_type(4))) float float4v;

__device__ unsigned short g_projB[(K_DIM / 8) * R_DIM * 8];        // 256 KB
__device__ unsigned short g_Tf[8 * (R_DIM / 8) * S_DIM * 8];       // 1 MB
__device__ float g_norms[M_ROWS];                                  // 16 KB

__device__ __forceinline__ unsigned short f2b(float f) {
  unsigned int u = __builtin_bit_cast(unsigned int, f);
  u += 0x7FFFu + ((u >> 16) & 1u);  // RNE
  return (unsigned short)(u >> 16);
}
__device__ __forceinline__ float b2f(unsigned short b) {
  unsigned int u = ((unsigned int)b) << 16;
  return __builtin_bit_cast(float, u);
}

// ---------------- Kernel 0: proj -> bf16 frag-major ----------------
// grid 128 x 256 thr: k = bid*8 + t>>5 (full 1024), n4 = (t&31)*4 (full 128).
__global__ __launch_bounds__(256) void prep_proj(const float* __restrict__ proj) {
  const int t = threadIdx.x;
  const int k = blockIdx.x * 8 + (t >> 5);
  const int n4 = (t & 31) * 4;
  const float4 v = *(const float4*)(proj + (size_t)k * R_DIM + n4);
  const unsigned short b0 = f2b(v.x), b1 = f2b(v.y), b2 = f2b(v.z), b3 = f2b(v.w);
  const int q = k >> 3, j = k & 7;
  g_projB[((size_t)q * R_DIM + n4 + 0) * 8 + j] = b0;
  g_projB[((size_t)q * R_DIM + n4 + 1) * 8 + j] = b1;
  g_projB[((size_t)q * R_DIM + n4 + 2) * 8 + j] = b2;
  g_projB[((size_t)q * R_DIM + n4 + 3) * 8 + j] = b3;
}

// ---------------- Kernel 1: T = batch@proj (MFMA) + norms ----------------
// 512 threads = 8 waves; wave w owns N-tile n0 = 16w. BM=16 rows/block, BK=64.
__global__ __launch_bounds__(512) void transform_kernel(const float* __restrict__ batch) {
  __shared__ __attribute__((aligned(16))) unsigned short As[2][8 * 16 * 8];   // [buf][q64][m][j]
  __shared__ __attribute__((aligned(16))) unsigned short Bs[2][8 * 128 * 8];  // [buf][q64][n][j]
  __shared__ float sh_norm[16];

  const int t = threadIdx.x;
  if (t < 16) sh_norm[t] = 0.0f;
  const int M0 = blockIdx.x * 16;
  const int lane = t & 63;
  const int wave = t >> 6;
  const int quad = lane >> 4;
  const int l16 = lane & 15;
  const int n0 = wave * 16;

  // A staging (threads 0..255): m = t>>4, k-index i = t&15 (k = 4i)
  const int am = t >> 4;
  const int ai = t & 15;
  const float* aptr = batch + (size_t)(M0 + am) * K_DIM + ai * 4;
  // B staging (all 512): contiguous 32 B each from g_projB chunk (16 KB/chunk)
  const unsigned short* bptr = g_projB + (size_t)t * 16;

  float4 apv = {0, 0, 0, 0};
  uint4 bpv0, bpv1;
  if (t < 256) apv = *(const float4*)(aptr);
  bpv0 = *(const uint4*)(bptr);
  bpv1 = *(const uint4*)(bptr + 8);

  float4v acc = {0.f, 0.f, 0.f, 0.f};

  for (int c = 0; c < 16; c++) {
    const int buf = c & 1;
    if (t < 256) {
      // k = 4*ai -> q64 = ai>>1, j0 = (ai&1)*4 ; pack 4 bf16 into one 8-B store
      unsigned short* dst = &As[buf][(((ai >> 1) * 16 + am) * 8) + (ai & 1) * 4];
      uint2 packed;
      packed.x = (unsigned int)f2b(apv.x) | ((unsigned int)f2b(apv.y) << 16);
      packed.y = (unsigned int)f2b(apv.z) | ((unsigned int)f2b(apv.w) << 16);
      *(uint2*)dst = packed;
    }
    *(uint4*)(&Bs[buf][t * 16]) = bpv0;
    *(uint4*)(&Bs[buf][t * 16 + 8]) = bpv1;
    __syncthreads();
    if (c < 15) {
      if (t < 256) apv = *(const float4*)(aptr + (c + 1) * 64);
      bpv0 = *(const uint4*)(bptr + (size_t)(c + 1) * 8192);
      bpv1 = *(const uint4*)(bptr + (size_t)(c + 1) * 8192 + 8);
    }
#pragma unroll
    for (int ks = 0; ks < 2; ks++) {
      const int q64 = ks * 4 + quad;
      const short8 af = *(const short8*)(&As[buf][(q64 * 16 + l16) * 8]);
      const short8 bf = *(const short8*)(&Bs[buf][(q64 * 128 + n0 + l16) * 8]);
      acc = __builtin_amdgcn_mfma_f32_16x16x32_bf16(af, bf, acc, 0, 0, 0);
    }
    // single barrier per iter: next store goes to buf^1, and barrier_{c+1}
    // guarantees all waves finished compute_c before any wave stores_{c+2}.
  }

  // Epilogue: lane holds T[M0 + quad*4 + r][n0 + l16] in acc[r].
  const int n = n0 + l16;
  float sq[4];
#pragma unroll
  for (int r = 0; r < 4; r++) {
    const unsigned short tb = f2b(acc[r]);
    const float tv = b2f(tb);
    sq[r] = tv * tv;
    const int gm = M0 + quad * 4 + r;
    const int bidx = gm >> 9, row = gm & 511;
    g_Tf[(((size_t)bidx * 16 + (n >> 3)) * S_DIM + row) * 8 + (n & 7)] = tb;
  }
#pragma unroll
  for (int r = 0; r < 4; r++) {
    float v = sq[r];
    v += __shfl_xor(v, 1);
    v += __shfl_xor(v, 2);
    v += __shfl_xor(v, 4);
    v += __shfl_xor(v, 8);
    if (l16 == 0) atomicAdd(&sh_norm[quad * 4 + r], v);
  }
  __syncthreads();
  if (t < 16) g_norms[M0 + t] = sh_norm[t];
}

// ---------------- Kernel 2: D = n_i + n_j - 2 * T T^T ----------------
// grid (8 jt, 8 it, 8 b), 256 thr = 4 waves; wave w: rows i0+16w x 64 cols.
__global__ __launch_bounds__(256) void dist_kernel(float* __restrict__ out) {
  const int t = threadIdx.x;
  const int lane = t & 63;
  const int wave = t >> 6;
  const int quad = lane >> 4;
  const int l16 = lane & 15;
  const int b = blockIdx.z;
  const int i0 = blockIdx.y * 64 + wave * 16;
  const int j0 = blockIdx.x * 64;

  const unsigned short* Tb = g_Tf + (size_t)b * 16 * S_DIM * 8;

  short8 af[4];
#pragma unroll
  for (int ks = 0; ks < 4; ks++) {
    const int q64 = ks * 4 + quad;
    af[ks] = *(const short8*)(Tb + ((size_t)q64 * S_DIM + i0 + l16) * 8);
  }
  short8 bfr[4][4];
#pragma unroll
  for (int jt = 0; jt < 4; jt++)
#pragma unroll
    for (int ks = 0; ks < 4; ks++) {
      const int q64 = ks * 4 + quad;
      bfr[jt][ks] = *(const short8*)(Tb + ((size_t)q64 * S_DIM + j0 + jt * 16 + l16) * 8);
    }

  float4v acc[4];
#pragma unroll
  for (int jt = 0; jt < 4; jt++) acc[jt] = (float4v){0.f, 0.f, 0.f, 0.f};
#pragma unroll
  for (int jt = 0; jt < 4; jt++)
#pragma unroll
    for (int ks = 0; ks < 4; ks++)
      acc[jt] = __builtin_amdgcn_mfma_f32_16x16x32_bf16(af[ks], bfr[jt][ks], acc[jt], 0, 0, 0);

  const float* nb = g_norms + (size_t)b * S_DIM;
  float ni[4];
#pragma unroll
  for (int r = 0; r < 4; r++) ni[r] = nb[i0 + quad * 4 + r];

  float* ob = out + (size_t)b * S_DIM * S_DIM;
#pragma unroll
  for (int jt = 0; jt < 4; jt++) {
    const float nj = nb[j0 + jt * 16 + l16];
#pragma unroll
    for (int r = 0; r < 4; r++) {
      const int i = i0 + quad * 4 + r;
      const int j = j0 + jt * 16 + l16;
      ob[(size_t)i * S_DIM + j] = ni[r] + nj - 2.0f * acc[jt][r];
    }
  }
}

extern "C" void kernel_launch(void* const* d_in, const int* in_sizes, int n_in,
                              void* d_out, int out_size, void* d_ws, size_t ws_size,
                              hipStream_t stream) {
  const float* batch = (const float*)d_in[0];
  const float* proj = (const float*)d_in[1];
  float* out = (float*)d_out;
  hipLaunchKernelGGL(prep_proj, dim3(128), dim3(256), 0, stream, proj);
  hipLaunchKernelGGL(transform_kernel, dim3(256), dim3(512), 0, stream, batch);
  hipLaunchKernelGGL(dist_kernel, dim3(8, 8, 8), dim3(256), 0, stream, out);
}

// Round 4
// 76.622 us; speedup vs baseline: 1.4516x; 1.0591x over previous
//
#include <hip/hip_runtime.h>
#include <hip/hip_bf16.h>

// DistanceProbe via bf16 MFMA:
//   T = batch@proj  (M=4096, K=1024, N=128), stored bf16 fragment-major
//   D[b,i,j] = n_i + n_j - 2*(T T^T)[b,i,j], norms from bf16-rounded T
//
// Kernel 0: proj fp32 [1024][128] -> g_projB bf16 frag-major [k/8][n][k&7]
// Kernel 1: GEMM (MFMA 16x16x32 bf16). BM=16, BN=64 (half), BK=128.
//           grid (2 halves, 256 m-tiles) = 512 blocks -> 2 blocks/CU so the
//           two blocks' barrier stalls overlap (m114 wave-level overlap).
//           8 barrier rounds (vs 16) halves exposed HBM latency.
//           Per-half partial norms -> g_normsP[half][row] (no cross-block atomics).
// Kernel 2: Gram + distance epilogue, fragments straight from L2; norms = P0+P1.

#define S_DIM 512
#define K_DIM 1024
#define R_DIM 128
#define M_ROWS 4096  // 8*512

typedef __attribute__((ext_vector_type(8))) short short8;
typedef __attribute__((ext_vector_type(4))) float float4v;

__device__ unsigned short g_projB[(K_DIM / 8) * R_DIM * 8];   // [q][n][j], 256 KB
__device__ unsigned short g_Tf[8 * (R_DIM / 8) * S_DIM * 8];  // [b][n/8][row][j], 1 MB
__device__ float g_normsP[2][M_ROWS];                         // per-half partial norms

__device__ __forceinline__ unsigned short f2b(float f) {
  unsigned int u = __builtin_bit_cast(unsigned int, f);
  u += 0x7FFFu + ((u >> 16) & 1u);  // RNE
  return (unsigned short)(u >> 16);
}
__device__ __forceinline__ float b2f(unsigned short b) {
  unsigned int u = ((unsigned int)b) << 16;
  return __builtin_bit_cast(float, u);
}

// ---------------- Kernel 0: proj -> bf16 frag-major ----------------
// grid 128 x 256 thr: k = bid*8 + t>>5 (full 1024), n4 = (t&31)*4 (full 128).
__global__ __launch_bounds__(256) void prep_proj(const float* __restrict__ proj) {
  const int t = threadIdx.x;
  const int k = blockIdx.x * 8 + (t >> 5);
  const int n4 = (t & 31) * 4;
  const float4 v = *(const float4*)(proj + (size_t)k * R_DIM + n4);
  const unsigned short b0 = f2b(v.x), b1 = f2b(v.y), b2 = f2b(v.z), b3 = f2b(v.w);
  const int q = k >> 3, j = k & 7;
  g_projB[((size_t)q * R_DIM + n4 + 0) * 8 + j] = b0;
  g_projB[((size_t)q * R_DIM + n4 + 1) * 8 + j] = b1;
  g_projB[((size_t)q * R_DIM + n4 + 2) * 8 + j] = b2;
  g_projB[((size_t)q * R_DIM + n4 + 3) * 8 + j] = b3;
}

// ---------------- Kernel 1: T = batch@proj (MFMA) + partial norms ----------------
// 256 threads = 4 waves; wave w owns n-subtile n0 = 16w within this block's 64-col half.
// BK=128 -> 8 c-iterations, 4 MFMAs/wave/iter. Register-prefetch double-buffered LDS,
// single barrier per iteration (store_{c+1} to buf^1 only after barrier_c, which
// guarantees all waves finished MFMA_{c-1} on buf^1).
__global__ __launch_bounds__(256) void transform_kernel(const float* __restrict__ batch) {
  // A: chunk index = q*16 + m  (16 q-units x 16 m x 8 bf16) = 4 KB/buf
  // B: chunk index = q*64 + n  (16 q-units x 64 n x 8 bf16) = 16 KB/buf
  // Both: staging writes are lane-contiguous 16B chunks, frag reads are
  // l16-contiguous 16B chunks -> <=2-way bank aliasing (free, m136).
  __shared__ __attribute__((aligned(16))) unsigned short As[2][16 * 16 * 8];
  __shared__ __attribute__((aligned(16))) unsigned short Bs[2][16 * 64 * 8];
  __shared__ float sh_norm[16];

  const int t = threadIdx.x;
  if (t < 16) sh_norm[t] = 0.0f;
  const int half = blockIdx.x;        // 0/1 -> n columns [0,64) / [64,128)
  const int M0 = blockIdx.y * 16;
  const int nb64 = half * 64;
  const int lane = t & 63;
  const int wave = t >> 6;
  const int quad = lane >> 4;
  const int l16 = lane & 15;
  const int n0 = wave * 16;

  // A staging: thread t -> (q = t>>4, m = t&15); loads 8 fp32 (32 B) of row M0+m
  // at k = c*128 + q*8. LDS store to chunk q*16+m == t -> contiguous.
  const int aq = t >> 4;
  const int am = t & 15;
  const float* aptr = batch + (size_t)(M0 + am) * K_DIM + aq * 8;
  // B staging: thread t -> n = t&63 (contiguous), q = wave*4 + s, s=0..3.
  const unsigned short* bptr =
      g_projB + ((size_t)(wave * 4) * R_DIM + nb64 + (t & 63)) * 8;

  float4 a0 = *(const float4*)(aptr);
  float4 a1 = *(const float4*)(aptr + 4);
  uint4 bv0 = *(const uint4*)(bptr);
  uint4 bv1 = *(const uint4*)(bptr + R_DIM * 8);
  uint4 bv2 = *(const uint4*)(bptr + 2 * R_DIM * 8);
  uint4 bv3 = *(const uint4*)(bptr + 3 * R_DIM * 8);

  float4v acc = {0.f, 0.f, 0.f, 0.f};

  for (int c = 0; c < 8; c++) {
    const int buf = c & 1;
    // pack 8 fp32 -> 8 bf16 -> one b128 LDS store
    uint4 ap;
    ap.x = (unsigned int)f2b(a0.x) | ((unsigned int)f2b(a0.y) << 16);
    ap.y = (unsigned int)f2b(a0.z) | ((unsigned int)f2b(a0.w) << 16);
    ap.z = (unsigned int)f2b(a1.x) | ((unsigned int)f2b(a1.y) << 16);
    ap.w = (unsigned int)f2b(a1.z) | ((unsigned int)f2b(a1.w) << 16);
    *(uint4*)(&As[buf][(size_t)t * 8]) = ap;  // chunk aq*16+am == t
    *(uint4*)(&Bs[buf][((size_t)(wave * 4 + 0) * 64 + (t & 63)) * 8]) = bv0;
    *(uint4*)(&Bs[buf][((size_t)(wave * 4 + 1) * 64 + (t & 63)) * 8]) = bv1;
    *(uint4*)(&Bs[buf][((size_t)(wave * 4 + 2) * 64 + (t & 63)) * 8]) = bv2;
    *(uint4*)(&Bs[buf][((size_t)(wave * 4 + 3) * 64 + (t & 63)) * 8]) = bv3;
    __syncthreads();
    if (c < 7) {
      a0 = *(const float4*)(aptr + (c + 1) * 128);
      a1 = *(const float4*)(aptr + (c + 1) * 128 + 4);
      const unsigned short* bp = bptr + (size_t)(c + 1) * 16 * R_DIM * 8;
      bv0 = *(const uint4*)(bp);
      bv1 = *(const uint4*)(bp + R_DIM * 8);
      bv2 = *(const uint4*)(bp + 2 * R_DIM * 8);
      bv3 = *(const uint4*)(bp + 3 * R_DIM * 8);
    }
#pragma unroll
    for (int ks = 0; ks < 4; ks++) {
      const int q = ks * 4 + quad;
      const short8 af = *(const short8*)(&As[buf][((size_t)q * 16 + l16) * 8]);
      const short8 bf = *(const short8*)(&Bs[buf][((size_t)q * 64 + n0 + l16) * 8]);
      acc = __builtin_amdgcn_mfma_f32_16x16x32_bf16(af, bf, acc, 0, 0, 0);
    }
  }

  // Epilogue: lane holds T[M0 + quad*4 + r][nb64 + n0 + l16] in acc[r].
  const int n = nb64 + n0 + l16;
  float sq[4];
#pragma unroll
  for (int r = 0; r < 4; r++) {
    const unsigned short tb = f2b(acc[r]);
    const float tv = b2f(tb);
    sq[r] = tv * tv;
    const int gm = M0 + quad * 4 + r;
    const int bidx = gm >> 9, row = gm & 511;
    g_Tf[(((size_t)bidx * 16 + (n >> 3)) * S_DIM + row) * 8 + (n & 7)] = tb;
  }
#pragma unroll
  for (int r = 0; r < 4; r++) {
    float v = sq[r];
    v += __shfl_xor(v, 1);
    v += __shfl_xor(v, 2);
    v += __shfl_xor(v, 4);
    v += __shfl_xor(v, 8);
    if (l16 == 0) atomicAdd(&sh_norm[quad * 4 + r], v);
  }
  __syncthreads();
  if (t < 16) g_normsP[half][M0 + t] = sh_norm[t];
}

// ---------------- Kernel 2: D = n_i + n_j - 2 * T T^T ----------------
// grid (8 jt, 8 it, 8 b), 256 thr = 4 waves; wave w: rows i0+16w x 64 cols.
__global__ __launch_bounds__(256) void dist_kernel(float* __restrict__ out) {
  const int t = threadIdx.x;
  const int lane = t & 63;
  const int wave = t >> 6;
  const int quad = lane >> 4;
  const int l16 = lane & 15;
  const int b = blockIdx.z;
  const int i0 = blockIdx.y * 64 + wave * 16;
  const int j0 = blockIdx.x * 64;

  const unsigned short* Tb = g_Tf + (size_t)b * 16 * S_DIM * 8;

  short8 af[4];
#pragma unroll
  for (int ks = 0; ks < 4; ks++) {
    const int q64 = ks * 4 + quad;
    af[ks] = *(const short8*)(Tb + ((size_t)q64 * S_DIM + i0 + l16) * 8);
  }
  short8 bfr[4][4];
#pragma unroll
  for (int jt = 0; jt < 4; jt++)
#pragma unroll
    for (int ks = 0; ks < 4; ks++) {
      const int q64 = ks * 4 + quad;
      bfr[jt][ks] = *(const short8*)(Tb + ((size_t)q64 * S_DIM + j0 + jt * 16 + l16) * 8);
    }

  float4v acc[4];
#pragma unroll
  for (int jt = 0; jt < 4; jt++) acc[jt] = (float4v){0.f, 0.f, 0.f, 0.f};
#pragma unroll
  for (int jt = 0; jt < 4; jt++)
#pragma unroll
    for (int ks = 0; ks < 4; ks++)
      acc[jt] = __builtin_amdgcn_mfma_f32_16x16x32_bf16(af[ks], bfr[jt][ks], acc[jt], 0, 0, 0);

  const float* np0 = g_normsP[0] + (size_t)b * S_DIM;
  const float* np1 = g_normsP[1] + (size_t)b * S_DIM;
  float ni[4];
#pragma unroll
  for (int r = 0; r < 4; r++) {
    const int i = i0 + quad * 4 + r;
    ni[r] = np0[i] + np1[i];
  }

  float* ob = out + (size_t)b * S_DIM * S_DIM;
#pragma unroll
  for (int jt = 0; jt < 4; jt++) {
    const int j = j0 + jt * 16 + l16;
    const float nj = np0[j] + np1[j];
#pragma unroll
    for (int r = 0; r < 4; r++) {
      const int i = i0 + quad * 4 + r;
      ob[(size_t)i * S_DIM + j] = ni[r] + nj - 2.0f * acc[jt][r];
    }
  }
}

extern "C" void kernel_launch(void* const* d_in, const int* in_sizes, int n_in,
                              void* d_out, int out_size, void* d_ws, size_t ws_size,
                              hipStream_t stream) {
  const float* batch = (const float*)d_in[0];
  const float* proj = (const float*)d_in[1];
  float* out = (float*)d_out;
  hipLaunchKernelGGL(prep_proj, dim3(128), dim3(256), 0, stream, proj);
  hipLaunchKernelGGL(transform_kernel, dim3(2, 256), dim3(256), 0, stream, batch);
  hipLaunchKernelGGL(dist_kernel, dim3(8, 8, 8), dim3(256), 0, stream, out);
}